// Round 6
// baseline (11296.699 us; speedup 1.0000x reference)
//
#include <hip/hip_runtime.h>

typedef __attribute__((ext_vector_type(8))) short short8;       // bf16x8 MFMA frag
typedef __attribute__((ext_vector_type(8))) unsigned short ushort8;
typedef __attribute__((ext_vector_type(4))) float f32x4;
typedef __attribute__((ext_vector_type(4))) int i32x4;

#define T_STEPS 2048
#define NWG 32

static __device__ __forceinline__ unsigned short f2bf(float f) {
  unsigned u = __builtin_bit_cast(unsigned, f);
  unsigned r = u + 0x7fffu + ((u >> 16) & 1u);   // RNE
  return (unsigned short)(r >> 16);
}
static __device__ __forceinline__ float bf2f(unsigned short h) {
  unsigned u = ((unsigned)h) << 16;
  return __builtin_bit_cast(float, u);
}
static __device__ __forceinline__ float fast_sigmoid(float v) {
  return __builtin_amdgcn_rcpf(1.0f + __expf(-v));
}
static __device__ __forceinline__ float fast_tanh(float v) {
  // tanh(x) = 1 - 2/(e^{2x}+1); saturates correctly at both ends
  return 1.0f - 2.0f * __builtin_amdgcn_rcpf(1.0f + __expf(2.0f * v));
}

// Pack layout for W (both Wx and Wh, each (512 x 2048) row-major):
// p[s][g][kt][l][e] : s<32 (slice), g<4 (gate), kt<16 (K-tile), l<64, e<8
// element = W[k][c] with k = kt*32 + (l>>4)*8 + e ; c = g*512 + s*16 + (l&15)
//
// h exchange: hbuf[slot][plane][32*512] bf16, slot = t&1 holds h_t. Every
// ushort carries tag=(t>>1)&3 in its 2 mantissa LSBs (self-validating data;
// any cache staleness -> tag mismatch -> retry). Fast mode adds per-producer
// FLAGS (atomic RMW at the shared XCD L2 — atomics always execute at L2, so
// they are fresh regardless of L1 state) so the wait is a cheap 4B spin and
// the 64KB data sweep runs exactly once.
__global__ void prep_kernel(const float* __restrict__ Wx, const float* __restrict__ Wh,
                            const float* __restrict__ h0,
                            unsigned short* __restrict__ wxp, unsigned short* __restrict__ whp,
                            unsigned short* __restrict__ hbuf, int* __restrict__ ctl,
                            int* __restrict__ flags) {
  int idx = blockIdx.x * 256 + threadIdx.x;
  if (idx < 2097152) {
    int which = idx >> 20;
    int r = idx & 1048575;
    int e = r & 7;
    int l = (r >> 3) & 63;
    int kt = (r >> 9) & 15;
    int g = (r >> 13) & 3;
    int s = r >> 15;
    int k = kt * 32 + ((l >> 4) << 3) + e;
    int c = g * 512 + s * 16 + (l & 15);
    const float* W = which ? Wh : Wx;
    unsigned short* dst = which ? whp : wxp;
    dst[r] = f2bf(W[k * 2048 + c]);
  } else if (idx < 2105344) {
    int r2 = (idx - 2097152) * 2;          // pair of (b*512+k)
    float v0 = h0[r2], v1 = h0[r2 + 1];
    // tag(step 0) = 0 : force 2 LSBs of hi and lo to 0
    unsigned short hi0 = f2bf(v0) & 0xFFFCu, hi1 = f2bf(v1) & 0xFFFCu;
    unsigned short lo0 = f2bf(v0 - bf2f(hi0)) & 0xFFFCu;
    unsigned short lo1 = f2bf(v1 - bf2f(hi1)) & 0xFFFCu;
    // slot 0 (input of step 0): hi plane at 0, lo plane at 16384 (MALL-visible)
    __hip_atomic_store((unsigned*)&hbuf[r2], (unsigned)hi0 | ((unsigned)hi1 << 16),
                       __ATOMIC_RELAXED, __HIP_MEMORY_SCOPE_AGENT);
    __hip_atomic_store((unsigned*)&hbuf[16384 + r2], (unsigned)lo0 | ((unsigned)lo1 << 16),
                       __ATOMIC_RELAXED, __HIP_MEMORY_SCOPE_AGENT);
  } else {
    int j = idx - 2105344;
    // ctl[0..7] per-XCD tickets, ctl[8] winner (-1 / xcc / 100=mixed), ctl[9] mixed tickets
    if (j < 10)
      __hip_atomic_store(&ctl[j], (j == 8) ? -1 : 0,
                         __ATOMIC_RELAXED, __HIP_MEMORY_SCOPE_AGENT);
    else if (j < 10 + 1024)
      flags[j - 10] = 0;                   // 32 flags, 128B apart (dispatch flush publishes)
  }
}

// Transpose x (b,t,d) f32 -> xt (t,b,d) bf16 (one contiguous 32 KB block/step).
__global__ void xprep_kernel(const float* __restrict__ x, unsigned short* __restrict__ xb) {
  size_t i8 = ((size_t)blockIdx.x * 256 + threadIdx.x) * 8;
  int t = (int)(i8 >> 14);
  int r = (int)(i8 & 16383);
  int b = r >> 9;
  int d = r & 511;
  const float* src = x + ((size_t)b * 2048 + (size_t)t) * 512 + d;
  f32x4 a = *(const f32x4*)src;
  f32x4 c = *(const f32x4*)(src + 4);
  ushort8 o;
#pragma unroll
  for (int e = 0; e < 4; ++e) {
    o[e] = f2bf(a[e]);
    o[e + 4] = f2bf(c[e]);
  }
  *(ushort8*)(xb + i8) = o;
}

// 256 WGs (1/CU via LDS). Fast mode: the 32 WGs of one XCD win; h moves through
// write-through-L1 -> shared XCD L2 with plain loads/stores (tag-guarded);
// waiting is a per-producer flag spin via L2-point atomic RMWs (always fresh).
// Mixed fallback: round-3 agent-atomic (MALL) tagged protocol.
__global__ __launch_bounds__(256, 1) void scan_kernel(
    const unsigned short* __restrict__ xb, const float* __restrict__ bias,
    const unsigned short* __restrict__ wxp, const unsigned short* __restrict__ whp,
    unsigned short* __restrict__ hbuf, float* __restrict__ out, int* __restrict__ ctl,
    int* __restrict__ flags) {
  __shared__ unsigned short WxL[4][16][512];   // 64 KB  [g][ktglob][l*8+e]
  __shared__ unsigned short WhL[4][16][512];   // 64 KB
  __shared__ float gA[32][68];                 // 8.5 KB partial sums (padded)
  __shared__ float gB[32][68];                 // 8.5 KB
  __shared__ int s_slice, s_fast;

  const int tid = threadIdx.x;
  const int lane = tid & 63;
  const int gw = tid >> 6;                     // wave id == K-slice id

  // ---- XCD claim with timeout fallback (always terminates)
  if (tid == 0) {
    unsigned xcc;
    asm volatile("s_getreg_b32 %0, hwreg(HW_REG_XCC_ID)" : "=s"(xcc));
    xcc &= 7;
    int tk = __hip_atomic_fetch_add(&ctl[xcc], 1, __ATOMIC_RELAXED,
                                    __HIP_MEMORY_SCOPE_AGENT);
    int my = -1, fm = 1;
    if (tk < NWG) {
      if (tk == NWG - 1) {
        int e = -1;
        __hip_atomic_compare_exchange_strong(&ctl[8], &e, (int)xcc,
                                             __ATOMIC_RELAXED, __ATOMIC_RELAXED,
                                             __HIP_MEMORY_SCOPE_AGENT);
      }
      int w = -1;
      for (int sp = 0;; ++sp) {
        w = __hip_atomic_load(&ctl[8], __ATOMIC_RELAXED, __HIP_MEMORY_SCOPE_AGENT);
        if (w != -1) break;
        if (sp > 30000) {                       // ~ms-scale: no XCD filled -> mixed
          int e = -1;
          __hip_atomic_compare_exchange_strong(&ctl[8], &e, 100,
                                               __ATOMIC_RELAXED, __ATOMIC_RELAXED,
                                               __HIP_MEMORY_SCOPE_AGENT);
          w = __hip_atomic_load(&ctl[8], __ATOMIC_RELAXED, __HIP_MEMORY_SCOPE_AGENT);
          break;
        }
        __builtin_amdgcn_s_sleep(2);
      }
      if (w == (int)xcc) {
        my = tk;                                // fast: same-XCD crew
      } else if (w >= 100) {
        int mt = __hip_atomic_fetch_add(&ctl[9], 1, __ATOMIC_RELAXED,
                                        __HIP_MEMORY_SCOPE_AGENT);
        if (mt < NWG) { my = mt; fm = 0; }      // mixed: MALL protocol
      }
    }
    s_slice = my;
    s_fast = fm;
  }
  __syncthreads();
  const int s = s_slice;
  const int fast = s_fast;
  if (s < 0) return;

  // ---- stage packed W slices into LDS
  {
    const ushort8* sx = (const ushort8*)(wxp + (size_t)s * 32768);
    const ushort8* sh = (const ushort8*)(whp + (size_t)s * 32768);
    ushort8* dx = (ushort8*)&WxL[0][0][0];
    ushort8* dh = (ushort8*)&WhL[0][0][0];
    for (int i = tid; i < 4096; i += 256) {
      dx[i] = sx[i];
      dh[i] = sh[i];
    }
  }

  const int p0 = tid * 2;
  const int ob = p0 >> 4;        // batch 0..31
  const int oj = p0 & 15;        // even unit index
  float2 bias2[4];
#pragma unroll
  for (int g = 0; g < 4; ++g)
    bias2[g] = *(const float2*)&bias[g * 512 + s * 16 + oj];

  float c0 = 0.f, c1 = 0.f;
  const int arow = lane & 15;
  const int kgrp = (lane >> 4) * 8;
  int* wflag = flags + ((gw << 3) + (lane & 7)) * 32;   // my wave's 8 producers
  int* myflag = flags + s * 32;

  __syncthreads();

  // prologue: prefetch x A-frags for t=0 (plain cached loads)
  short8 xf0[4], xf1[4];
#pragma unroll
  for (int kt = 0; kt < 4; ++kt) {
    const int k0 = (gw << 7) + (kt << 5) + kgrp;
    xf0[kt] = *(const short8*)&xb[arow * 512 + k0];
    xf1[kt] = *(const short8*)&xb[(arow + 16) * 512 + k0];
  }

  for (int t = 0; t < T_STEPS; ++t) {
    const unsigned tp = 0x00010001u * (unsigned)((t >> 1) & 3);
    const unsigned short* hrd = hbuf + (t & 1) * 32768;
    i32x4 q[16];

    if (fast) {
      // ---- phase 1a: flag spin (L2-point RMW = always fresh, 4B, 8 lines/wave)
      if (t > 0) {
        int done = (lane >= 8);
        for (;;) {
          if (!done) {
            int old, zero = 0;
            asm volatile("global_atomic_add %0, %1, %2, off sc0\n\t"
                         "s_waitcnt vmcnt(0)"
                         : "=v"(old) : "v"(wflag), "v"(zero) : "memory");
            done = (old >= t);
          }
          if (__all(done)) break;
          __builtin_amdgcn_s_sleep(1);
        }
      }
      // ---- phase 1b: single tagged data sweep (retry only on L1 staleness)
      for (;;) {
#pragma unroll
        for (int kt = 0; kt < 4; ++kt) {
          const int k0 = (gw << 7) + (kt << 5) + kgrp;
          const unsigned short* pa = hrd + arow * 512 + k0;
          const unsigned short* pb = hrd + 16384 + arow * 512 + k0;
          const unsigned short* pc = hrd + (arow + 16) * 512 + k0;
          const unsigned short* pd = hrd + 16384 + (arow + 16) * 512 + k0;
          asm volatile("global_load_dwordx4 %0, %1, off" : "=v"(q[kt * 4 + 0]) : "v"(pa));
          asm volatile("global_load_dwordx4 %0, %1, off" : "=v"(q[kt * 4 + 1]) : "v"(pb));
          asm volatile("global_load_dwordx4 %0, %1, off" : "=v"(q[kt * 4 + 2]) : "v"(pc));
          asm volatile("global_load_dwordx4 %0, %1, off" : "=v"(q[kt * 4 + 3]) : "v"(pd));
        }
        asm volatile("s_waitcnt vmcnt(0)" ::: "memory");
        __builtin_amdgcn_sched_barrier(0);
        unsigned bad = 0;
#pragma unroll
        for (int i = 0; i < 16; ++i)
#pragma unroll
          for (int j = 0; j < 4; ++j)
            bad |= (((unsigned)q[i][j]) & 0x00030003u) ^ tp;
        if (__all(bad == 0)) break;
      }
    } else {
      const unsigned long long* hb64 = (const unsigned long long*)hrd;
      for (;;) {
#pragma unroll
        for (int kt = 0; kt < 4; ++kt) {
          const int k0 = (gw << 7) + (kt << 5) + kgrp;
          const int base[4] = {(arow * 512 + k0) >> 2, (16384 + arow * 512 + k0) >> 2,
                               ((arow + 16) * 512 + k0) >> 2,
                               (16384 + (arow + 16) * 512 + k0) >> 2};
#pragma unroll
          for (int m = 0; m < 4; ++m) {
            union { unsigned long long u[2]; i32x4 v; } uu;
            uu.u[0] = __hip_atomic_load(hb64 + base[m], __ATOMIC_RELAXED,
                                        __HIP_MEMORY_SCOPE_AGENT);
            uu.u[1] = __hip_atomic_load(hb64 + base[m] + 1, __ATOMIC_RELAXED,
                                        __HIP_MEMORY_SCOPE_AGENT);
            q[kt * 4 + m] = uu.v;
          }
        }
        unsigned bad = 0;
#pragma unroll
        for (int i = 0; i < 16; ++i)
#pragma unroll
          for (int j = 0; j < 4; ++j)
            bad |= (((unsigned)q[i][j]) & 0x00030003u) ^ tp;
        if (__all(bad == 0)) break;
      }
    }

    // ---- phase 2: MFMA
    f32x4 acc[4][2];
#pragma unroll
    for (int nt = 0; nt < 4; ++nt)
#pragma unroll
      for (int mt = 0; mt < 2; ++mt)
        acc[nt][mt] = (f32x4){0.f, 0.f, 0.f, 0.f};

#pragma unroll
    for (int kt = 0; kt < 4; ++kt) {
      const int ktg = (gw << 2) + kt;
      short8 hh0 = __builtin_bit_cast(short8, q[kt * 4 + 0]);
      short8 hl0 = __builtin_bit_cast(short8, q[kt * 4 + 1]);
      short8 hh1 = __builtin_bit_cast(short8, q[kt * 4 + 2]);
      short8 hl1 = __builtin_bit_cast(short8, q[kt * 4 + 3]);
#pragma unroll
      for (int nt = 0; nt < 4; ++nt) {
        short8 bx = *(const short8*)&WxL[nt][ktg][lane * 8];
        short8 bh = *(const short8*)&WhL[nt][ktg][lane * 8];
        acc[nt][0] = __builtin_amdgcn_mfma_f32_16x16x32_bf16(xf0[kt], bx, acc[nt][0], 0, 0, 0);
        acc[nt][0] = __builtin_amdgcn_mfma_f32_16x16x32_bf16(hh0, bh, acc[nt][0], 0, 0, 0);
        acc[nt][0] = __builtin_amdgcn_mfma_f32_16x16x32_bf16(hl0, bh, acc[nt][0], 0, 0, 0);
        acc[nt][1] = __builtin_amdgcn_mfma_f32_16x16x32_bf16(xf1[kt], bx, acc[nt][1], 0, 0, 0);
        acc[nt][1] = __builtin_amdgcn_mfma_f32_16x16x32_bf16(hh1, bh, acc[nt][1], 0, 0, 0);
        acc[nt][1] = __builtin_amdgcn_mfma_f32_16x16x32_bf16(hl1, bh, acc[nt][1], 0, 0, 0);
      }
    }

    // ---- phase 3: LDS partial-sum exchange (waves 2,3 store; 0,1 add)
    {
      float* dst = (gw & 1) ? &gB[0][0] : &gA[0][0];
      if (gw >= 2) {
#pragma unroll
        for (int nt = 0; nt < 4; ++nt)
#pragma unroll
          for (int mt = 0; mt < 2; ++mt)
#pragma unroll
            for (int r = 0; r < 4; ++r)
              dst[(mt * 16 + (lane >> 4) * 4 + r) * 68 + nt * 16 + (lane & 15)] =
                  acc[nt][mt][r];
      }
      __syncthreads();
      if (gw < 2) {
#pragma unroll
        for (int nt = 0; nt < 4; ++nt)
#pragma unroll
          for (int mt = 0; mt < 2; ++mt)
#pragma unroll
            for (int r = 0; r < 4; ++r)
              dst[(mt * 16 + (lane >> 4) * 4 + r) * 68 + nt * 16 + (lane & 15)] +=
                  acc[nt][mt][r];
      }
      __syncthreads();
    }

    // ---- phase 4: gates, c/h update (2 (batch,unit) pairs per thread)
    float2 v4[4];
#pragma unroll
    for (int g = 0; g < 4; ++g) {
      float2 a2 = *(float2*)&gA[ob][g * 16 + oj];
      float2 b2 = *(float2*)&gB[ob][g * 16 + oj];
      v4[g].x = a2.x + b2.x + bias2[g].x;
      v4[g].y = a2.y + b2.y + bias2[g].y;
    }
    float i0 = fast_sigmoid(v4[0].x), i1 = fast_sigmoid(v4[0].y);
    float f0 = fast_sigmoid(v4[1].x), f1 = fast_sigmoid(v4[1].y);
    float o0 = fast_sigmoid(v4[2].x), o1 = fast_sigmoid(v4[2].y);
    float g0 = fast_tanh(v4[3].x), g1 = fast_tanh(v4[3].y);
    c0 = f0 * c0 + i0 * g0;
    c1 = f1 * c1 + i1 * g1;
    float hv0 = o0 * fast_tanh(c0);
    float hv1 = o1 * fast_tanh(c1);

    // ---- phase 5: publish tagged h, drain, then flag bump (fast mode)
    const unsigned ntag = (unsigned)(((t + 1) >> 1) & 3);
    unsigned short hi0 = (unsigned short)((f2bf(hv0) & 0xFFFCu) | ntag);
    unsigned short hi1 = (unsigned short)((f2bf(hv1) & 0xFFFCu) | ntag);
    unsigned short lo0 = (unsigned short)((f2bf(hv0 - bf2f(hi0)) & 0xFFFCu) | ntag);
    unsigned short lo1 = (unsigned short)((f2bf(hv1 - bf2f(hi1)) & 0xFFFCu) | ntag);
    unsigned short* hwr = hbuf + ((t + 1) & 1) * 32768;
    const int hidx = ob * 512 + s * 16 + oj;
    unsigned whi = (unsigned)hi0 | ((unsigned)hi1 << 16);
    unsigned wlo = (unsigned)lo0 | ((unsigned)lo1 << 16);
    if (fast) {
      unsigned* pw1 = (unsigned*)&hwr[hidx];
      unsigned* pw2 = (unsigned*)&hwr[16384 + hidx];
      asm volatile("global_store_dword %0, %1, off" :: "v"(pw1), "v"(whi) : "memory");
      asm volatile("global_store_dword %0, %1, off" :: "v"(pw2), "v"(wlo) : "memory");
    } else {
      __hip_atomic_store((unsigned*)&hwr[hidx], whi, __ATOMIC_RELAXED,
                         __HIP_MEMORY_SCOPE_AGENT);
      __hip_atomic_store((unsigned*)&hwr[16384 + hidx], wlo, __ATOMIC_RELAXED,
                         __HIP_MEMORY_SCOPE_AGENT);
    }
    asm volatile("s_waitcnt vmcnt(0)" ::: "memory");
    __syncthreads();             // h in L2 for the whole WG + gbuf WAR guard
    if (fast && tid == 0) {
      int one = 1;
      asm volatile("global_atomic_add %0, %1, off" :: "v"(myflag), "v"(one) : "memory");
    }

    // ---- phase 6 (off the publish path): out store + next x prefetch
    float2 hv2 = {hv0, hv1};
    *(float2*)&out[(size_t)ob * (2048 * 512) + (size_t)t * 512 + s * 16 + oj] = hv2;
    {
      const int tn = (t + 1 < T_STEPS) ? (t + 1) : t;
      const unsigned short* xt1 = xb + (size_t)tn * 16384;
#pragma unroll
      for (int kt = 0; kt < 4; ++kt) {
        const int k0 = (gw << 7) + (kt << 5) + kgrp;
        xf0[kt] = *(const short8*)&xt1[arow * 512 + k0];
        xf1[kt] = *(const short8*)&xt1[(arow + 16) * 512 + k0];
      }
    }
  }
}

extern "C" void kernel_launch(void* const* d_in, const int* in_sizes, int n_in,
                              void* d_out, int out_size, void* d_ws, size_t ws_size,
                              hipStream_t stream) {
  const float* x = (const float*)d_in[0];     // (32, 2048, 512) f32
  const float* h0 = (const float*)d_in[1];    // (32, 512) f32
  const float* Wx = (const float*)d_in[2];    // (512, 2048) f32
  const float* Wh = (const float*)d_in[3];    // (512, 2048) f32
  const float* bias = (const float*)d_in[4];  // (2048,) f32
  float* out = (float*)d_out;

  char* ws = (char*)d_ws;
  unsigned short* wxp = (unsigned short*)(ws);                            // 2 MB
  unsigned short* whp = (unsigned short*)(ws + (2u << 20));               // 2 MB
  unsigned short* hbuf = (unsigned short*)(ws + (4u << 20));              // 128 KB
  int* ctl = (int*)(ws + (4u << 20) + (256u << 10));                      // 40 B
  int* flags = (int*)(ws + (5u << 20));                                   // 4 KB
  unsigned short* xb = (unsigned short*)(ws + (8u << 20));                // 64 MB

  hipLaunchKernelGGL(prep_kernel, dim3(8229), dim3(256), 0, stream,
                     Wx, Wh, h0, wxp, whp, hbuf, ctl, flags);
  hipLaunchKernelGGL(xprep_kernel, dim3(16384), dim3(256), 0, stream, x, xb);
  hipLaunchKernelGGL(scan_kernel, dim3(256), dim3(256), 0, stream,
                     xb, bias, wxp, whp, hbuf, out, ctl, flags);
}

// Round 7
// 10494.424 us; speedup vs baseline: 1.0764x; 1.0764x over previous
//
#include <hip/hip_runtime.h>

typedef __attribute__((ext_vector_type(8))) short short8;       // bf16x8 MFMA frag
typedef __attribute__((ext_vector_type(8))) unsigned short ushort8;
typedef __attribute__((ext_vector_type(4))) float f32x4;
typedef __attribute__((ext_vector_type(4))) int i32x4;

#define T_STEPS 2048
#define NWG 32

static __device__ __forceinline__ unsigned short f2bf(float f) {
  unsigned u = __builtin_bit_cast(unsigned, f);
  unsigned r = u + 0x7fffu + ((u >> 16) & 1u);   // RNE
  return (unsigned short)(r >> 16);
}
static __device__ __forceinline__ float bf2f(unsigned short h) {
  unsigned u = ((unsigned)h) << 16;
  return __builtin_bit_cast(float, u);
}
static __device__ __forceinline__ float fast_sigmoid(float v) {
  return __builtin_amdgcn_rcpf(1.0f + __expf(-v));
}
static __device__ __forceinline__ float fast_tanh(float v) {
  // tanh(x) = 1 - 2/(e^{2x}+1); saturates correctly at both ends
  return 1.0f - 2.0f * __builtin_amdgcn_rcpf(1.0f + __expf(2.0f * v));
}

// Pack layout for W (both Wx and Wh, each (512 x 2048) row-major):
// p[s][g][kt][l][e] : s<32 (slice), g<4 (gate), kt<16 (K-tile), l<64, e<8
// element = W[k][c] with k = kt*32 + (l>>4)*8 + e ; c = g*512 + s*16 + (l&15)
//
// h exchange: hbuf[slot][plane][32*512] bf16, slot = t&1 holds h_t. Every
// ushort carries tag=(t>>1)&3 in its 2 mantissa LSBs (self-validating data;
// staleness -> tag mismatch -> retry; liveness via L2-fresh sc0 loads, with
// L1-capacity-eviction as the proven fallback). Skew < 2 steps (a WG
// publishes h_{t+1} only after all 4 waves validated h_t); ring alias t vs
// t-2 differs by 1 mod 4; replay leftovers / 0xAA poison never match t=0,1.
__global__ void prep_kernel(const float* __restrict__ Wx, const float* __restrict__ Wh,
                            const float* __restrict__ h0,
                            unsigned short* __restrict__ wxp, unsigned short* __restrict__ whp,
                            unsigned short* __restrict__ hbuf, int* __restrict__ ctl) {
  int idx = blockIdx.x * 256 + threadIdx.x;
  if (idx < 2097152) {
    int which = idx >> 20;
    int r = idx & 1048575;
    int e = r & 7;
    int l = (r >> 3) & 63;
    int kt = (r >> 9) & 15;
    int g = (r >> 13) & 3;
    int s = r >> 15;
    int k = kt * 32 + ((l >> 4) << 3) + e;
    int c = g * 512 + s * 16 + (l & 15);
    const float* W = which ? Wh : Wx;
    unsigned short* dst = which ? whp : wxp;
    dst[r] = f2bf(W[k * 2048 + c]);
  } else if (idx < 2105344) {
    int r2 = (idx - 2097152) * 2;          // pair of (b*512+k)
    float v0 = h0[r2], v1 = h0[r2 + 1];
    // tag(step 0) = 0 : force 2 LSBs of hi and lo to 0
    unsigned short hi0 = f2bf(v0) & 0xFFFCu, hi1 = f2bf(v1) & 0xFFFCu;
    unsigned short lo0 = f2bf(v0 - bf2f(hi0)) & 0xFFFCu;
    unsigned short lo1 = f2bf(v1 - bf2f(hi1)) & 0xFFFCu;
    // slot 0 (input of step 0): hi plane at 0, lo plane at 16384 (MALL-visible)
    __hip_atomic_store((unsigned*)&hbuf[r2], (unsigned)hi0 | ((unsigned)hi1 << 16),
                       __ATOMIC_RELAXED, __HIP_MEMORY_SCOPE_AGENT);
    __hip_atomic_store((unsigned*)&hbuf[16384 + r2], (unsigned)lo0 | ((unsigned)lo1 << 16),
                       __ATOMIC_RELAXED, __HIP_MEMORY_SCOPE_AGENT);
  } else {
    int j = idx - 2105344;
    // ctl[0..7] per-XCD tickets, ctl[8] winner (-1 / xcc / 100=mixed), ctl[9] mixed tickets
    if (j < 10)
      __hip_atomic_store(&ctl[j], (j == 8) ? -1 : 0,
                         __ATOMIC_RELAXED, __HIP_MEMORY_SCOPE_AGENT);
  }
}

// Transpose x (b,t,d) f32 -> xt (t,b,d) bf16 (one contiguous 32 KB block/step).
__global__ void xprep_kernel(const float* __restrict__ x, unsigned short* __restrict__ xb) {
  size_t i8 = ((size_t)blockIdx.x * 256 + threadIdx.x) * 8;
  int t = (int)(i8 >> 14);
  int r = (int)(i8 & 16383);
  int b = r >> 9;
  int d = r & 511;
  const float* src = x + ((size_t)b * 2048 + (size_t)t) * 512 + d;
  f32x4 a = *(const f32x4*)src;
  f32x4 c = *(const f32x4*)(src + 4);
  ushort8 o;
#pragma unroll
  for (int e = 0; e < 4; ++e) {
    o[e] = f2bf(a[e]);
    o[e + 4] = f2bf(c[e]);
  }
  *(ushort8*)(xb + i8) = o;
}

// 256 WGs (1/CU via LDS). Fast mode: the 32 WGs of one XCD win; producers
// publish h with plain write-through stores; consumers poll with sc0 loads
// (SE scope = serviced at the shared XCD L2, never a stale L1 line), tags
// make any residual staleness harmless. Mixed fallback: MALL agent atomics.
__global__ __launch_bounds__(256, 1) void scan_kernel(
    const unsigned short* __restrict__ xb, const float* __restrict__ bias,
    const unsigned short* __restrict__ wxp, const unsigned short* __restrict__ whp,
    unsigned short* __restrict__ hbuf, float* __restrict__ out, int* __restrict__ ctl) {
  __shared__ unsigned short WxL[4][16][512];   // 64 KB  [g][ktglob][l*8+e]
  __shared__ unsigned short WhL[4][16][512];   // 64 KB
  __shared__ float gA[32][68];                 // 8.5 KB partial sums (padded)
  __shared__ float gB[32][68];                 // 8.5 KB
  __shared__ int s_slice, s_fast;

  const int tid = threadIdx.x;
  const int lane = tid & 63;
  const int gw = tid >> 6;                     // wave id == K-slice id

  // ---- XCD claim with timeout fallback (always terminates)
  if (tid == 0) {
    unsigned xcc;
    asm volatile("s_getreg_b32 %0, hwreg(HW_REG_XCC_ID)" : "=s"(xcc));
    xcc &= 7;
    int tk = __hip_atomic_fetch_add(&ctl[xcc], 1, __ATOMIC_RELAXED,
                                    __HIP_MEMORY_SCOPE_AGENT);
    int my = -1, fm = 1;
    if (tk < NWG) {
      if (tk == NWG - 1) {
        int e = -1;
        __hip_atomic_compare_exchange_strong(&ctl[8], &e, (int)xcc,
                                             __ATOMIC_RELAXED, __ATOMIC_RELAXED,
                                             __HIP_MEMORY_SCOPE_AGENT);
      }
      int w = -1;
      for (int sp = 0;; ++sp) {
        w = __hip_atomic_load(&ctl[8], __ATOMIC_RELAXED, __HIP_MEMORY_SCOPE_AGENT);
        if (w != -1) break;
        if (sp > 30000) {                       // ~ms-scale: no XCD filled -> mixed
          int e = -1;
          __hip_atomic_compare_exchange_strong(&ctl[8], &e, 100,
                                               __ATOMIC_RELAXED, __ATOMIC_RELAXED,
                                               __HIP_MEMORY_SCOPE_AGENT);
          w = __hip_atomic_load(&ctl[8], __ATOMIC_RELAXED, __HIP_MEMORY_SCOPE_AGENT);
          break;
        }
        __builtin_amdgcn_s_sleep(2);
      }
      if (w == (int)xcc) {
        my = tk;                                // fast: same-XCD crew
      } else if (w >= 100) {
        int mt = __hip_atomic_fetch_add(&ctl[9], 1, __ATOMIC_RELAXED,
                                        __HIP_MEMORY_SCOPE_AGENT);
        if (mt < NWG) { my = mt; fm = 0; }      // mixed: MALL protocol
      }
    }
    s_slice = my;
    s_fast = fm;
  }
  __syncthreads();
  const int s = s_slice;
  const int fast = s_fast;
  if (s < 0) return;

  // ---- stage packed W slices into LDS
  {
    const ushort8* sx = (const ushort8*)(wxp + (size_t)s * 32768);
    const ushort8* sh = (const ushort8*)(whp + (size_t)s * 32768);
    ushort8* dx = (ushort8*)&WxL[0][0][0];
    ushort8* dh = (ushort8*)&WhL[0][0][0];
    for (int i = tid; i < 4096; i += 256) {
      dx[i] = sx[i];
      dh[i] = sh[i];
    }
  }

  const int p0 = tid * 2;
  const int ob = p0 >> 4;        // batch 0..31
  const int oj = p0 & 15;        // even unit index
  float2 bias2[4];
#pragma unroll
  for (int g = 0; g < 4; ++g)
    bias2[g] = *(const float2*)&bias[g * 512 + s * 16 + oj];

  float c0 = 0.f, c1 = 0.f;
  const int arow = lane & 15;
  const int kgrp = (lane >> 4) * 8;

  __syncthreads();

  // prologue: prefetch x A-frags for t=0 (plain cached loads)
  short8 xf0[4], xf1[4];
#pragma unroll
  for (int kt = 0; kt < 4; ++kt) {
    const int k0 = (gw << 7) + (kt << 5) + kgrp;
    xf0[kt] = *(const short8*)&xb[arow * 512 + k0];
    xf1[kt] = *(const short8*)&xb[(arow + 16) * 512 + k0];
  }

  for (int t = 0; t < T_STEPS; ++t) {
    // ---- phase 1: tagged poll; the polls ARE the data loads
    const unsigned tp = 0x00010001u * (unsigned)((t >> 1) & 3);
    const unsigned short* hrd = hbuf + (t & 1) * 32768;
    i32x4 q[16];
    if (fast) {
      for (;;) {
#pragma unroll
        for (int kt = 0; kt < 4; ++kt) {
          const int k0 = (gw << 7) + (kt << 5) + kgrp;
          const unsigned short* pa = hrd + arow * 512 + k0;
          const unsigned short* pb = hrd + 16384 + arow * 512 + k0;
          const unsigned short* pc = hrd + (arow + 16) * 512 + k0;
          const unsigned short* pd = hrd + 16384 + (arow + 16) * 512 + k0;
          // sc0 = SE scope: no SE-level cache exists, so serviced at the
          // shared XCD L2 -> always-fresh data, no L1 staleness thrash.
          asm volatile("global_load_dwordx4 %0, %1, off sc0" : "=v"(q[kt * 4 + 0]) : "v"(pa));
          asm volatile("global_load_dwordx4 %0, %1, off sc0" : "=v"(q[kt * 4 + 1]) : "v"(pb));
          asm volatile("global_load_dwordx4 %0, %1, off sc0" : "=v"(q[kt * 4 + 2]) : "v"(pc));
          asm volatile("global_load_dwordx4 %0, %1, off sc0" : "=v"(q[kt * 4 + 3]) : "v"(pd));
        }
        asm volatile("s_waitcnt vmcnt(0)" ::: "memory");
        __builtin_amdgcn_sched_barrier(0);
        unsigned bad = 0;
#pragma unroll
        for (int i = 0; i < 16; ++i)
#pragma unroll
          for (int j = 0; j < 4; ++j)
            bad |= (((unsigned)q[i][j]) & 0x00030003u) ^ tp;
        if (__all(bad == 0)) break;
      }
    } else {
      const unsigned long long* hb64 = (const unsigned long long*)hrd;
      for (;;) {
#pragma unroll
        for (int kt = 0; kt < 4; ++kt) {
          const int k0 = (gw << 7) + (kt << 5) + kgrp;
          const int base[4] = {(arow * 512 + k0) >> 2, (16384 + arow * 512 + k0) >> 2,
                               ((arow + 16) * 512 + k0) >> 2,
                               (16384 + (arow + 16) * 512 + k0) >> 2};
#pragma unroll
          for (int m = 0; m < 4; ++m) {
            union { unsigned long long u[2]; i32x4 v; } uu;
            uu.u[0] = __hip_atomic_load(hb64 + base[m], __ATOMIC_RELAXED,
                                        __HIP_MEMORY_SCOPE_AGENT);
            uu.u[1] = __hip_atomic_load(hb64 + base[m] + 1, __ATOMIC_RELAXED,
                                        __HIP_MEMORY_SCOPE_AGENT);
            q[kt * 4 + m] = uu.v;
          }
        }
        unsigned bad = 0;
#pragma unroll
        for (int i = 0; i < 16; ++i)
#pragma unroll
          for (int j = 0; j < 4; ++j)
            bad |= (((unsigned)q[i][j]) & 0x00030003u) ^ tp;
        if (__all(bad == 0)) break;
      }
    }

    // ---- phase 2: MFMA
    f32x4 acc[4][2];
#pragma unroll
    for (int nt = 0; nt < 4; ++nt)
#pragma unroll
      for (int mt = 0; mt < 2; ++mt)
        acc[nt][mt] = (f32x4){0.f, 0.f, 0.f, 0.f};

#pragma unroll
    for (int kt = 0; kt < 4; ++kt) {
      const int ktg = (gw << 2) + kt;
      short8 hh0 = __builtin_bit_cast(short8, q[kt * 4 + 0]);
      short8 hl0 = __builtin_bit_cast(short8, q[kt * 4 + 1]);
      short8 hh1 = __builtin_bit_cast(short8, q[kt * 4 + 2]);
      short8 hl1 = __builtin_bit_cast(short8, q[kt * 4 + 3]);
#pragma unroll
      for (int nt = 0; nt < 4; ++nt) {
        short8 bx = *(const short8*)&WxL[nt][ktg][lane * 8];
        short8 bh = *(const short8*)&WhL[nt][ktg][lane * 8];
        acc[nt][0] = __builtin_amdgcn_mfma_f32_16x16x32_bf16(xf0[kt], bx, acc[nt][0], 0, 0, 0);
        acc[nt][0] = __builtin_amdgcn_mfma_f32_16x16x32_bf16(hh0, bh, acc[nt][0], 0, 0, 0);
        acc[nt][0] = __builtin_amdgcn_mfma_f32_16x16x32_bf16(hl0, bh, acc[nt][0], 0, 0, 0);
        acc[nt][1] = __builtin_amdgcn_mfma_f32_16x16x32_bf16(xf1[kt], bx, acc[nt][1], 0, 0, 0);
        acc[nt][1] = __builtin_amdgcn_mfma_f32_16x16x32_bf16(hh1, bh, acc[nt][1], 0, 0, 0);
        acc[nt][1] = __builtin_amdgcn_mfma_f32_16x16x32_bf16(hl1, bh, acc[nt][1], 0, 0, 0);
      }
    }

    // ---- phase 3: LDS partial-sum exchange (waves 2,3 store; 0,1 add)
    {
      float* dst = (gw & 1) ? &gB[0][0] : &gA[0][0];
      if (gw >= 2) {
#pragma unroll
        for (int nt = 0; nt < 4; ++nt)
#pragma unroll
          for (int mt = 0; mt < 2; ++mt)
#pragma unroll
            for (int r = 0; r < 4; ++r)
              dst[(mt * 16 + (lane >> 4) * 4 + r) * 68 + nt * 16 + (lane & 15)] =
                  acc[nt][mt][r];
      }
      __syncthreads();
      if (gw < 2) {
#pragma unroll
        for (int nt = 0; nt < 4; ++nt)
#pragma unroll
          for (int mt = 0; mt < 2; ++mt)
#pragma unroll
            for (int r = 0; r < 4; ++r)
              dst[(mt * 16 + (lane >> 4) * 4 + r) * 68 + nt * 16 + (lane & 15)] +=
                  acc[nt][mt][r];
      }
      __syncthreads();
    }

    // ---- phase 4: gates, c/h update (2 (batch,unit) pairs per thread)
    float2 v4[4];
#pragma unroll
    for (int g = 0; g < 4; ++g) {
      float2 a2 = *(float2*)&gA[ob][g * 16 + oj];
      float2 b2 = *(float2*)&gB[ob][g * 16 + oj];
      v4[g].x = a2.x + b2.x + bias2[g].x;
      v4[g].y = a2.y + b2.y + bias2[g].y;
    }
    float i0 = fast_sigmoid(v4[0].x), i1 = fast_sigmoid(v4[0].y);
    float f0 = fast_sigmoid(v4[1].x), f1 = fast_sigmoid(v4[1].y);
    float o0 = fast_sigmoid(v4[2].x), o1 = fast_sigmoid(v4[2].y);
    float g0 = fast_tanh(v4[3].x), g1 = fast_tanh(v4[3].y);
    c0 = f0 * c0 + i0 * g0;
    c1 = f1 * c1 + i1 * g1;
    float hv0 = o0 * fast_tanh(c0);
    float hv1 = o1 * fast_tanh(c1);

    // ---- phase 5: publish tagged h (fire-and-forget; write-through reaches L2)
    const unsigned ntag = (unsigned)(((t + 1) >> 1) & 3);
    unsigned short hi0 = (unsigned short)((f2bf(hv0) & 0xFFFCu) | ntag);
    unsigned short hi1 = (unsigned short)((f2bf(hv1) & 0xFFFCu) | ntag);
    unsigned short lo0 = (unsigned short)((f2bf(hv0 - bf2f(hi0)) & 0xFFFCu) | ntag);
    unsigned short lo1 = (unsigned short)((f2bf(hv1 - bf2f(hi1)) & 0xFFFCu) | ntag);
    unsigned short* hwr = hbuf + ((t + 1) & 1) * 32768;
    const int hidx = ob * 512 + s * 16 + oj;
    unsigned whi = (unsigned)hi0 | ((unsigned)hi1 << 16);
    unsigned wlo = (unsigned)lo0 | ((unsigned)lo1 << 16);
    if (fast) {
      unsigned* pw1 = (unsigned*)&hwr[hidx];
      unsigned* pw2 = (unsigned*)&hwr[16384 + hidx];
      asm volatile("global_store_dword %0, %1, off" :: "v"(pw1), "v"(whi) : "memory");
      asm volatile("global_store_dword %0, %1, off" :: "v"(pw2), "v"(wlo) : "memory");
    } else {
      __hip_atomic_store((unsigned*)&hwr[hidx], whi, __ATOMIC_RELAXED,
                         __HIP_MEMORY_SCOPE_AGENT);
      __hip_atomic_store((unsigned*)&hwr[16384 + hidx], wlo, __ATOMIC_RELAXED,
                         __HIP_MEMORY_SCOPE_AGENT);
    }

    // gbuf WAR guard (only 2 dword stores in flight -> cheap vmcnt drain)
    __syncthreads();

    // ---- phase 6 (floats into next poll): out store + next x prefetch
    float2 hv2 = {hv0, hv1};
    *(float2*)&out[(size_t)ob * (2048 * 512) + (size_t)t * 512 + s * 16 + oj] = hv2;
    {
      const int tn = (t + 1 < T_STEPS) ? (t + 1) : t;
      const unsigned short* xt1 = xb + (size_t)tn * 16384;
#pragma unroll
      for (int kt = 0; kt < 4; ++kt) {
        const int k0 = (gw << 7) + (kt << 5) + kgrp;
        xf0[kt] = *(const short8*)&xt1[arow * 512 + k0];
        xf1[kt] = *(const short8*)&xt1[(arow + 16) * 512 + k0];
      }
    }
  }
}

extern "C" void kernel_launch(void* const* d_in, const int* in_sizes, int n_in,
                              void* d_out, int out_size, void* d_ws, size_t ws_size,
                              hipStream_t stream) {
  const float* x = (const float*)d_in[0];     // (32, 2048, 512) f32
  const float* h0 = (const float*)d_in[1];    // (32, 512) f32
  const float* Wx = (const float*)d_in[2];    // (512, 2048) f32
  const float* Wh = (const float*)d_in[3];    // (512, 2048) f32
  const float* bias = (const float*)d_in[4];  // (2048,) f32
  float* out = (float*)d_out;

  char* ws = (char*)d_ws;
  unsigned short* wxp = (unsigned short*)(ws);                            // 2 MB
  unsigned short* whp = (unsigned short*)(ws + (2u << 20));               // 2 MB
  unsigned short* hbuf = (unsigned short*)(ws + (4u << 20));              // 128 KB
  int* ctl = (int*)(ws + (4u << 20) + (256u << 10));                      // 40 B
  unsigned short* xb = (unsigned short*)(ws + (8u << 20));                // 64 MB

  hipLaunchKernelGGL(prep_kernel, dim3(8225), dim3(256), 0, stream,
                     Wx, Wh, h0, wxp, whp, hbuf, ctl);
  hipLaunchKernelGGL(xprep_kernel, dim3(16384), dim3(256), 0, stream, x, xb);
  hipLaunchKernelGGL(scan_kernel, dim3(256), dim3(256), 0, stream,
                     xb, bias, wxp, whp, hbuf, out, ctl);
}

// Round 9
// 8828.907 us; speedup vs baseline: 1.2795x; 1.1886x over previous
//
#include <hip/hip_runtime.h>

typedef __attribute__((ext_vector_type(8))) short short8;       // bf16x8 MFMA frag
typedef __attribute__((ext_vector_type(8))) unsigned short ushort8;
typedef __attribute__((ext_vector_type(4))) float f32x4;
typedef __attribute__((ext_vector_type(4))) int i32x4;

#define T_STEPS 2048

static __device__ __forceinline__ unsigned short f2bf(float f) {
  unsigned u = __builtin_bit_cast(unsigned, f);
  unsigned r = u + 0x7fffu + ((u >> 16) & 1u);   // RNE
  return (unsigned short)(r >> 16);
}
static __device__ __forceinline__ float bf2f(unsigned short h) {
  unsigned u = ((unsigned)h) << 16;
  return __builtin_bit_cast(float, u);
}
static __device__ __forceinline__ float fast_sigmoid(float v) {
  return __builtin_amdgcn_rcpf(1.0f + __expf(-v));
}
static __device__ __forceinline__ float fast_tanh(float v) {
  return 1.0f - 2.0f * __builtin_amdgcn_rcpf(1.0f + __expf(2.0f * v));
}

// W pack (proven r1-r7): p[s][g][kt][l][e], element = W[k][c],
// k = kt*32 + (l>>4)*8 + e ; c = g*512 + s*16 + (l&15).
//
// h exchange: per-GROUP 16-slot ring. hbuf[group][slot][plane][4*512] bf16;
// slot = t&15 holds h_t; every ushort carries tag=(t>>4)&3 in its 2 mantissa
// LSBs. Liveness design (NO unverified cache ops):
//  - producers publish via agent-scope atomic dword stores (r3-proven visible)
//  - consumers: ONE plain wide-load attempt (its L1 lines were capacity-
//    evicted since the slot's last use 16 steps ago -> fresh L2/MALL fill),
//    tag-checked; on failure -> agent-scope u64 atomic load loop (r3-proven
//    live at MALL). Worst case = r3-style timing; hang impossible.
// Ring safety: skew between slowest reader of h_t and fastest writer is
// 2 slots (transitive publish proof) << 16. Replay/poison staleness: stale
// tags differ from expected (mod-4 stepping + prep rewrite of slot 0).
__global__ void prep_kernel(const float* __restrict__ Wx, const float* __restrict__ Wh,
                            const float* __restrict__ h0,
                            unsigned short* __restrict__ wxp, unsigned short* __restrict__ whp,
                            unsigned short* __restrict__ hbuf, int* __restrict__ ctl) {
  int idx = blockIdx.x * 256 + threadIdx.x;
  if (idx < 2097152) {
    int which = idx >> 20;
    int r = idx & 1048575;
    int e = r & 7;
    int l = (r >> 3) & 63;
    int kt = (r >> 9) & 15;
    int g = (r >> 13) & 3;
    int s = r >> 15;
    int k = kt * 32 + ((l >> 4) << 3) + e;
    int c = g * 512 + s * 16 + (l & 15);
    const float* W = which ? Wh : Wx;
    unsigned short* dst = which ? whp : wxp;
    dst[r] = f2bf(W[k * 2048 + c]);
  } else if (idx < 2097152 + 16384) {
    int i = idx - 2097152;                 // b*512 + k
    int bg = i >> 9;                       // global batch
    int k = i & 511;
    int g = bg >> 2, bl = bg & 3;
    float v = h0[i];
    unsigned short hi = f2bf(v) & 0xFFFCu;                 // tag(step 0)=0
    unsigned short lo = f2bf(v - bf2f(hi)) & 0xFFFCu;
    unsigned short* d = hbuf + g * 65536;                  // group base, slot 0
    d[bl * 512 + k] = hi;
    d[2048 + bl * 512 + k] = lo;
  } else if (idx < 2097152 + 16384 + 9) {
    ctl[idx - (2097152 + 16384)] = 0;      // ctl[0..7]=XCD tickets, ctl[8]=orphan rank
  }
}

// Transpose x (b,t,d) f32 -> xt (t,b,d) bf16 (unchanged).
__global__ void xprep_kernel(const float* __restrict__ x, unsigned short* __restrict__ xb) {
  size_t i8 = ((size_t)blockIdx.x * 256 + threadIdx.x) * 8;
  int t = (int)(i8 >> 14);
  int r = (int)(i8 & 16383);
  int b = r >> 9;
  int d = r & 511;
  const float* src = x + ((size_t)b * 2048 + (size_t)t) * 512 + d;
  f32x4 a = *(const f32x4*)src;
  f32x4 c = *(const f32x4*)(src + 4);
  ushort8 o;
#pragma unroll
  for (int e = 0; e < 4; ++e) {
    o[e] = f2bf(a[e]);
    o[e + 4] = f2bf(c[e]);
  }
  *(ushort8*)(xb + i8) = o;
}

// 256 WGs @ 1 WG/CU (136KB LDS), grid == CU count (guide-blessed co-residency).
// Group g owns batches 4g..4g+3; slice s owns units [16s,16s+16).
// Assignment: per-XCD tickets; global settle (sum==256, monotonic counters =>
// exact final snapshot); overflow WGs adopt orphan (group,slice) pairs
// deterministically. Homogeneous group (>=32 local) => direct-L2 first
// attempt; else pure MALL path. Wave w = K-slice [128w,128w+128).
__global__ __launch_bounds__(256, 1) void scan_kernel(
    const unsigned short* __restrict__ xb, const float* __restrict__ bias,
    const unsigned short* __restrict__ wxp, const unsigned short* __restrict__ whp,
    unsigned short* __restrict__ hbuf, float* __restrict__ out, int* __restrict__ ctl) {
  __shared__ unsigned short WxL[4][16][512];   // 64 KB
  __shared__ unsigned short WhL[4][16][512];   // 64 KB
  __shared__ float gLDS[2][4][4][4][16];       // 8 KB [parity][wave][gate][batch][unit]
  __shared__ int s_g, s_s, s_dir;

  const int tid = threadIdx.x;
  const int lane = tid & 63;
  const int gw = tid >> 6;                     // wave id == K-slice id

  if (tid == 0) {
    unsigned xcc;
    asm volatile("s_getreg_b32 %0, hwreg(HW_REG_XCC_ID)" : "=s"(xcc));
    xcc &= 7;
    int tk = __hip_atomic_fetch_add(&ctl[xcc], 1, __ATOMIC_RELAXED,
                                    __HIP_MEMORY_SCOPE_AGENT);
    // settle: all 256 WGs ticket before anyone proceeds (counters monotonic;
    // sum==256 implies every per-XCD read equals its final value)
    int c[8];
    for (;;) {
      int tot = 0;
#pragma unroll
      for (int x = 0; x < 8; ++x) {
        c[x] = __hip_atomic_load(&ctl[x], __ATOMIC_RELAXED, __HIP_MEMORY_SCOPE_AGENT);
        tot += c[x];
      }
      if (tot >= 256) break;
      __builtin_amdgcn_s_sleep(2);
    }
    int g = -1, s = -1, dir = 0;
    if (tk < 32) {
      g = (int)xcc;
      s = tk;
      dir = (c[xcc] >= 32);                    // group fully local => direct L2 attempt
    } else {
      int rank = __hip_atomic_fetch_add(&ctl[8], 1, __ATOMIC_RELAXED,
                                        __HIP_MEMORY_SCOPE_AGENT);
      int acc = 0;
      for (int x = 0; x < 8; ++x) {
        int n = 32 - c[x];
        if (n < 0) n = 0;
        if (g < 0 && rank < acc + n) { g = x; s = c[x] + (rank - acc); }
        acc += n;
      }
      dir = 0;                                 // foreign adopter => MALL only
    }
    s_g = g; s_s = s; s_dir = dir;
  }
  __syncthreads();
  const int g = s_g, s = s_s, use_direct = s_dir;
  if (s < 0 || g < 0) return;                  // safety (counts guarantee not taken)

  // ---- stage packed W slice s into LDS, then preload ALL B-frags to regs
  {
    const ushort8* sx = (const ushort8*)(wxp + (size_t)s * 32768);
    const ushort8* sh = (const ushort8*)(whp + (size_t)s * 32768);
    ushort8* dx = (ushort8*)&WxL[0][0][0];
    ushort8* dh = (ushort8*)&WhL[0][0][0];
    for (int i = tid; i < 4096; i += 256) {
      dx[i] = sx[i];
      dh[i] = sh[i];
    }
  }
  __syncthreads();
  short8 wxf[4][4], whf[4][4];                 // [kt][nt] : 128 VGPRs (1 wave/SIMD)
#pragma unroll
  for (int kt = 0; kt < 4; ++kt)
#pragma unroll
    for (int nt = 0; nt < 4; ++nt) {
      const int ktg = (gw << 2) + kt;
      wxf[kt][nt] = *(const short8*)&WxL[nt][ktg][lane * 8];
      whf[kt][nt] = *(const short8*)&WhL[nt][ktg][lane * 8];
    }

  const int brow = lane & 3;                   // batch row (A rows 4-15 duplicate)
  const int kgrp = (lane >> 4) * 8;
  const int gb = lane >> 4;                    // gate-phase batch 0..3
  const int gu = lane & 15;                    // gate-phase unit 0..15
  float bias4[4];
#pragma unroll
  for (int gg2 = 0; gg2 < 4; ++gg2)
    bias4[gg2] = bias[gg2 * 512 + s * 16 + gu];
  float c = 0.f;

  unsigned short* hb = hbuf + g * 65536;       // group ring base (16 slots x 4096)
  float* outbase = out + (size_t)(g * 4 + gb) * (2048 * 512) + s * 16 + gu;
  const int xrow = (g * 4 + brow) * 512;
  const int shfl_src = ((lane >> 3) << 4) + ((lane & 7) << 1);  // publish pairing

  short8 xf[4];
#pragma unroll
  for (int kt = 0; kt < 4; ++kt) {
    const int k0 = (gw << 7) + (kt << 5) + kgrp;
    xf[kt] = *(const short8*)&xb[xrow + k0];
  }

  for (int t = 0; t < T_STEPS; ++t) {
    // ---- phase 1: acquire h_t (tag-validated)
    const unsigned tag = (unsigned)((t >> 4) & 3);
    const unsigned tp32 = 0x00010001u * tag;
    const unsigned short* hrd = hb + (t & 15) * 4096;
    i32x4 q[8];
    bool ok = false;
    if (use_direct) {
      // one plain wide attempt: slot lines were capacity-evicted from L1
      // (>=190KB of traffic since last use) -> fresh L2 fill
#pragma unroll
      for (int kt = 0; kt < 4; ++kt) {
        const int k0 = (gw << 7) + (kt << 5) + kgrp;
        q[kt * 2 + 0] = *(const i32x4*)(hrd + brow * 512 + k0);
        q[kt * 2 + 1] = *(const i32x4*)(hrd + 2048 + brow * 512 + k0);
      }
      unsigned bad = 0;
#pragma unroll
      for (int i = 0; i < 8; ++i)
#pragma unroll
        for (int j = 0; j < 4; ++j)
          bad |= (((unsigned)q[i][j]) & 0x00030003u) ^ tp32;
      ok = __all(bad == 0);
    }
    if (!ok) {
      // proven-live MALL path: agent-scope u64 atomic loads until tags match
      const unsigned long long tp64 = 0x0001000100010001ull * (unsigned long long)tag;
      const unsigned long long* h64 = (const unsigned long long*)hrd;
      for (;;) {
        unsigned long long bad = 0;
#pragma unroll
        for (int kt = 0; kt < 4; ++kt) {
          const int k0 = (gw << 7) + (kt << 5) + kgrp;
          const int bi = (brow * 512 + k0) >> 2;
          const int bj = (2048 + brow * 512 + k0) >> 2;
          union { unsigned long long u[2]; i32x4 v; } a, b;
          a.u[0] = __hip_atomic_load(h64 + bi, __ATOMIC_RELAXED, __HIP_MEMORY_SCOPE_AGENT);
          a.u[1] = __hip_atomic_load(h64 + bi + 1, __ATOMIC_RELAXED, __HIP_MEMORY_SCOPE_AGENT);
          b.u[0] = __hip_atomic_load(h64 + bj, __ATOMIC_RELAXED, __HIP_MEMORY_SCOPE_AGENT);
          b.u[1] = __hip_atomic_load(h64 + bj + 1, __ATOMIC_RELAXED, __HIP_MEMORY_SCOPE_AGENT);
          q[kt * 2 + 0] = a.v;
          q[kt * 2 + 1] = b.v;
          bad |= (a.u[0] & 0x0003000300030003ull) ^ tp64;
          bad |= (a.u[1] & 0x0003000300030003ull) ^ tp64;
          bad |= (b.u[0] & 0x0003000300030003ull) ^ tp64;
          bad |= (b.u[1] & 0x0003000300030003ull) ^ tp64;
        }
        if (__all(bad == 0)) break;
        __builtin_amdgcn_s_sleep(1);
      }
    }

    // ---- phase 2: MFMA (A from q/xf, B preloaded in regs)
    f32x4 acc[4];
#pragma unroll
    for (int nt = 0; nt < 4; ++nt) acc[nt] = (f32x4){0.f, 0.f, 0.f, 0.f};
#pragma unroll
    for (int kt = 0; kt < 4; ++kt) {
      short8 hh = __builtin_bit_cast(short8, q[kt * 2 + 0]);
      short8 hl = __builtin_bit_cast(short8, q[kt * 2 + 1]);
#pragma unroll
      for (int nt = 0; nt < 4; ++nt) {
        acc[nt] = __builtin_amdgcn_mfma_f32_16x16x32_bf16(xf[kt], wxf[kt][nt], acc[nt], 0, 0, 0);
        acc[nt] = __builtin_amdgcn_mfma_f32_16x16x32_bf16(hh, whf[kt][nt], acc[nt], 0, 0, 0);
        acc[nt] = __builtin_amdgcn_mfma_f32_16x16x32_bf16(hl, whf[kt][nt], acc[nt], 0, 0, 0);
      }
    }

    // ---- phase 3: K-partial exchange (parity gLDS; ONE barrier per step)
    if (lane < 16) {
#pragma unroll
      for (int nt = 0; nt < 4; ++nt)
#pragma unroll
        for (int r = 0; r < 4; ++r)
          gLDS[t & 1][gw][nt][r][lane] = acc[nt][r];   // D: col=lane (unit), reg r=batch
    }
    __syncthreads();

    // ---- phase 4: gates (all waves redundantly; identical results)
    float v4[4];
#pragma unroll
    for (int gg2 = 0; gg2 < 4; ++gg2) {
      float sum = bias4[gg2];
#pragma unroll
      for (int w = 0; w < 4; ++w) sum += gLDS[t & 1][w][gg2][gb][gu];
      v4[gg2] = sum;
    }
    float ig = fast_sigmoid(v4[0]);
    float fg = fast_sigmoid(v4[1]);
    float og = fast_sigmoid(v4[2]);
    float gg3 = fast_tanh(v4[3]);
    c = fg * c + ig * gg3;
    float h = og * fast_tanh(c);

    // ---- phase 5: wave 0 publishes tagged h (agent dword stores) + fp32 out
    if (gw == 0) {
      const unsigned ntag = (unsigned)(((t + 1) >> 4) & 3);
      float ha = __shfl(h, shfl_src);
      float hbv = __shfl(h, shfl_src + 1);
      unsigned short hiA = (unsigned short)((f2bf(ha) & 0xFFFCu) | ntag);
      unsigned short loA = (unsigned short)((f2bf(ha - bf2f(hiA)) & 0xFFFCu) | ntag);
      unsigned short hiB = (unsigned short)((f2bf(hbv) & 0xFFFCu) | ntag);
      unsigned short loB = (unsigned short)((f2bf(hbv - bf2f(hiB)) & 0xFFFCu) | ntag);
      unsigned whi = (unsigned)hiA | ((unsigned)hiB << 16);
      unsigned wlo = (unsigned)loA | ((unsigned)loB << 16);
      if (lane < 32) {
        const int b = lane >> 3, u2 = (lane & 7) * 2;
        unsigned short* wr = hb + ((t + 1) & 15) * 4096;
        __hip_atomic_store((unsigned*)&wr[b * 512 + s * 16 + u2], whi,
                           __ATOMIC_RELAXED, __HIP_MEMORY_SCOPE_AGENT);
        __hip_atomic_store((unsigned*)&wr[2048 + b * 512 + s * 16 + u2], wlo,
                           __ATOMIC_RELAXED, __HIP_MEMORY_SCOPE_AGENT);
      }
      outbase[(size_t)t * 512] = h;
    }

    // ---- phase 6: x prefetch for t+1 (drains before next MFMA via compiler waits)
    {
      const int tn = (t + 1 < T_STEPS) ? (t + 1) : t;
      const unsigned short* xt1 = xb + (size_t)tn * 16384;
#pragma unroll
      for (int kt = 0; kt < 4; ++kt) {
        const int k0 = (gw << 7) + (kt << 5) + kgrp;
        xf[kt] = *(const short8*)&xt1[xrow + k0];
      }
    }
  }
}

extern "C" void kernel_launch(void* const* d_in, const int* in_sizes, int n_in,
                              void* d_out, int out_size, void* d_ws, size_t ws_size,
                              hipStream_t stream) {
  const float* x = (const float*)d_in[0];     // (32, 2048, 512) f32
  const float* h0 = (const float*)d_in[1];    // (32, 512) f32
  const float* Wx = (const float*)d_in[2];    // (512, 2048) f32
  const float* Wh = (const float*)d_in[3];    // (512, 2048) f32
  const float* bias = (const float*)d_in[4];  // (2048,) f32
  float* out = (float*)d_out;

  char* ws = (char*)d_ws;
  unsigned short* wxp = (unsigned short*)(ws);                            // 2 MB
  unsigned short* whp = (unsigned short*)(ws + (2u << 20));               // 2 MB
  unsigned short* hbuf = (unsigned short*)(ws + (4u << 20));              // 1 MB (8 groups x 128KB)
  int* ctl = (int*)(ws + (5u << 20) + (512u << 10));                      // 36 B
  unsigned short* xb = (unsigned short*)(ws + (8u << 20));                // 64 MB

  hipLaunchKernelGGL(prep_kernel, dim3(8257), dim3(256), 0, stream,
                     Wx, Wh, h0, wxp, whp, hbuf, ctl);
  hipLaunchKernelGGL(xprep_kernel, dim3(16384), dim3(256), 0, stream, x, xb);
  hipLaunchKernelGGL(scan_kernel, dim3(256), dim3(256), 0, stream,
                     xb, bias, wxp, whp, hbuf, out, ctl);
}

// Round 10
// 6606.824 us; speedup vs baseline: 1.7099x; 1.3363x over previous
//
#include <hip/hip_runtime.h>

typedef __attribute__((ext_vector_type(8))) short short8;       // bf16x8 MFMA frag
typedef __attribute__((ext_vector_type(8))) unsigned short ushort8;
typedef __attribute__((ext_vector_type(4))) float f32x4;
typedef __attribute__((ext_vector_type(4))) int i32x4;

#define T_STEPS 2048

static __device__ __forceinline__ unsigned short f2bf(float f) {
  unsigned u = __builtin_bit_cast(unsigned, f);
  unsigned r = u + 0x7fffu + ((u >> 16) & 1u);   // RNE
  return (unsigned short)(r >> 16);
}
static __device__ __forceinline__ float bf2f(unsigned short h) {
  unsigned u = ((unsigned)h) << 16;
  return __builtin_bit_cast(float, u);
}
static __device__ __forceinline__ float fast_sigmoid(float v) {
  return __builtin_amdgcn_rcpf(1.0f + __expf(-v));
}
static __device__ __forceinline__ float fast_tanh(float v) {
  return 1.0f - 2.0f * __builtin_amdgcn_rcpf(1.0f + __expf(2.0f * v));
}

// W pack (proven): p[s][g][kt][l][e], element = W[k][c],
// k = kt*32 + (l>>4)*8 + e ; c = g*512 + s*16 + (l&15).
//
// h exchange: per-GROUP 16-slot ring, hbuf[group][slot][plane][4*512] bf16;
// slot=t&15, tag=(t>>4)&3 in 2 LSBs of every ushort (self-validating).
// NEW: producer publishes data (plain write-through -> shared XCD L2 for
// homogeneous groups; agent stores otherwise), drains vmcnt, then bumps a
// per-(group,slice) FLAG via agent-scope atomic (r6-proven fresh+live).
// Consumers spin on 8 flags (4B RMWs, 64x less MALL traffic than data
// polling) then do ONE plain data read: fresh because (a) flag => producer
// stores completed to L2, (b) 16-slot ring => consumer's L1 lines for this
// slot were capacity-evicted (>=380KB per-CU traffic per ring lap). Tag
// mismatch (can't happen per (a)+(b), kept as net) -> r9's MALL loop.
__global__ void prep_kernel(const float* __restrict__ Wx, const float* __restrict__ Wh,
                            const float* __restrict__ h0,
                            unsigned short* __restrict__ wxp, unsigned short* __restrict__ whp,
                            unsigned short* __restrict__ hbuf, int* __restrict__ ctl,
                            int* __restrict__ flags) {
  int idx = blockIdx.x * 256 + threadIdx.x;
  if (idx < 2097152) {
    int which = idx >> 20;
    int r = idx & 1048575;
    int e = r & 7;
    int l = (r >> 3) & 63;
    int kt = (r >> 9) & 15;
    int g = (r >> 13) & 3;
    int s = r >> 15;
    int k = kt * 32 + ((l >> 4) << 3) + e;
    int c = g * 512 + s * 16 + (l & 15);
    const float* W = which ? Wh : Wx;
    unsigned short* dst = which ? whp : wxp;
    dst[r] = f2bf(W[k * 2048 + c]);
  } else if (idx < 2097152 + 16384) {
    int i = idx - 2097152;                 // b*512 + k
    int bg = i >> 9;
    int k = i & 511;
    int g = bg >> 2, bl = bg & 3;
    float v = h0[i];
    unsigned short hi = f2bf(v) & 0xFFFCu;                 // tag(step 0)=0
    unsigned short lo = f2bf(v - bf2f(hi)) & 0xFFFCu;
    unsigned short* d = hbuf + g * 65536;                  // group base, slot 0
    d[bl * 512 + k] = hi;
    d[2048 + bl * 512 + k] = lo;
  } else if (idx < 2097152 + 16384 + 9) {
    ctl[idx - (2097152 + 16384)] = 0;      // ctl[0..7]=XCD tickets, ctl[8]=orphan rank
  } else if (idx < 2097152 + 16384 + 9 + 8192) {
    flags[idx - (2097152 + 16384 + 9)] = 0;   // 8 groups x 32 slices x 32-int spacing
  }
}

// Transpose x (b,t,d) f32 -> xt (t,b,d) bf16 (unchanged).
__global__ void xprep_kernel(const float* __restrict__ x, unsigned short* __restrict__ xb) {
  size_t i8 = ((size_t)blockIdx.x * 256 + threadIdx.x) * 8;
  int t = (int)(i8 >> 14);
  int r = (int)(i8 & 16383);
  int b = r >> 9;
  int d = r & 511;
  const float* src = x + ((size_t)b * 2048 + (size_t)t) * 512 + d;
  f32x4 a = *(const f32x4*)src;
  f32x4 c = *(const f32x4*)(src + 4);
  ushort8 o;
#pragma unroll
  for (int e = 0; e < 4; ++e) {
    o[e] = f2bf(a[e]);
    o[e + 4] = f2bf(c[e]);
  }
  *(ushort8*)(xb + i8) = o;
}

__global__ __launch_bounds__(256, 1) void scan_kernel(
    const unsigned short* __restrict__ xb, const float* __restrict__ bias,
    const unsigned short* __restrict__ wxp, const unsigned short* __restrict__ whp,
    unsigned short* __restrict__ hbuf, float* __restrict__ out, int* __restrict__ ctl,
    int* __restrict__ flags) {
  __shared__ unsigned short WxL[4][16][512];   // 64 KB
  __shared__ unsigned short WhL[4][16][512];   // 64 KB
  __shared__ float gLDS[2][4][4][4][16];       // 8 KB [parity][wave][gate][batch][unit]
  __shared__ int s_g, s_s, s_dir;

  const int tid = threadIdx.x;
  const int lane = tid & 63;
  const int gw = tid >> 6;                     // wave id == K-slice id

  if (tid == 0) {
    unsigned xcc;
    asm volatile("s_getreg_b32 %0, hwreg(HW_REG_XCC_ID)" : "=s"(xcc));
    xcc &= 7;
    int tk = __hip_atomic_fetch_add(&ctl[xcc], 1, __ATOMIC_RELAXED,
                                    __HIP_MEMORY_SCOPE_AGENT);
    int c[8];
    for (;;) {                                 // settle: all 256 ticket first
      int tot = 0;
#pragma unroll
      for (int x = 0; x < 8; ++x) {
        c[x] = __hip_atomic_load(&ctl[x], __ATOMIC_RELAXED, __HIP_MEMORY_SCOPE_AGENT);
        tot += c[x];
      }
      if (tot >= 256) break;
      __builtin_amdgcn_s_sleep(2);
    }
    int g = -1, s = -1, dir = 0;
    if (tk < 32) {
      g = (int)xcc;
      s = tk;
      dir = (c[xcc] >= 32);                    // fully local group => L2 fast path
    } else {
      int rank = __hip_atomic_fetch_add(&ctl[8], 1, __ATOMIC_RELAXED,
                                        __HIP_MEMORY_SCOPE_AGENT);
      int acc2 = 0;
      for (int x = 0; x < 8; ++x) {
        int n = 32 - c[x];
        if (n < 0) n = 0;
        if (g < 0 && rank < acc2 + n) { g = x; s = c[x] + (rank - acc2); }
        acc2 += n;
      }
      dir = 0;
    }
    s_g = g; s_s = s; s_dir = dir;
  }
  __syncthreads();
  const int g = s_g, s = s_s, use_direct = s_dir;
  if (s < 0 || g < 0) return;

  {
    const ushort8* sx = (const ushort8*)(wxp + (size_t)s * 32768);
    const ushort8* sh = (const ushort8*)(whp + (size_t)s * 32768);
    ushort8* dx = (ushort8*)&WxL[0][0][0];
    ushort8* dh = (ushort8*)&WhL[0][0][0];
    for (int i = tid; i < 4096; i += 256) {
      dx[i] = sx[i];
      dh[i] = sh[i];
    }
  }
  __syncthreads();
  short8 wxf[4][4], whf[4][4];                 // [kt][nt]
#pragma unroll
  for (int kt = 0; kt < 4; ++kt)
#pragma unroll
    for (int nt = 0; nt < 4; ++nt) {
      const int ktg = (gw << 2) + kt;
      wxf[kt][nt] = *(const short8*)&WxL[nt][ktg][lane * 8];
      whf[kt][nt] = *(const short8*)&WhL[nt][ktg][lane * 8];
    }

  const int brow = lane & 3;
  const int kgrp = (lane >> 4) * 8;
  const int gb = lane >> 4;                    // gate-phase batch 0..3
  const int gu = lane & 15;                    // gate-phase unit 0..15
  float bias4[4];
#pragma unroll
  for (int gg2 = 0; gg2 < 4; ++gg2)
    bias4[gg2] = bias[gg2 * 512 + s * 16 + gu];
  float c = 0.f;

  unsigned short* hb = hbuf + g * 65536;
  int* gflags = flags + g * 1024;
  int* wflag = gflags + ((gw << 3) + (lane & 7)) * 32;   // my wave's 8 producers
  int* myflag = gflags + s * 32;
  float* outbase = out + (size_t)(g * 4 + gb) * (2048 * 512) + s * 16 + gu;
  const int xrow = (g * 4 + brow) * 512;
  const int shfl_src = ((lane >> 3) << 4) + ((lane & 7) << 1);

  short8 xf[4];
#pragma unroll
  for (int kt = 0; kt < 4; ++kt) {
    const int k0 = (gw << 7) + (kt << 5) + kgrp;
    xf[kt] = *(const short8*)&xb[xrow + k0];
  }

  for (int t = 0; t < T_STEPS; ++t) {
    // ---- phase A: x-part MFMAs (h-independent; runs in the wait shadow)
    f32x4 acc[4];
#pragma unroll
    for (int nt = 0; nt < 4; ++nt) acc[nt] = (f32x4){0.f, 0.f, 0.f, 0.f};
#pragma unroll
    for (int kt = 0; kt < 4; ++kt)
#pragma unroll
      for (int nt = 0; nt < 4; ++nt)
        acc[nt] = __builtin_amdgcn_mfma_f32_16x16x32_bf16(xf[kt], wxf[kt][nt], acc[nt], 0, 0, 0);

    // ---- phase B: flag wait (4B agent RMW per producer; r6-proven)
    if (t > 0) {
      int done = (lane >= 8);
      for (;;) {
        if (!done) {
          int old, zero = 0;
          asm volatile("global_atomic_add %0, %1, %2, off sc0\n\t"
                       "s_waitcnt vmcnt(0)"
                       : "=v"(old) : "v"(wflag), "v"(zero) : "memory");
          done = (old >= t);
        }
        if (__all(done)) break;
        __builtin_amdgcn_s_sleep(1);
      }
    }

    // ---- phase C: data read (one plain L2 read; tag net; MALL fallback)
    const unsigned tag = (unsigned)((t >> 4) & 3);
    const unsigned tp32 = 0x00010001u * tag;
    const unsigned short* hrd = hb + (t & 15) * 4096;
    i32x4 q[8];
    bool ok = false;
    if (use_direct) {
#pragma unroll
      for (int kt = 0; kt < 4; ++kt) {
        const int k0 = (gw << 7) + (kt << 5) + kgrp;
        q[kt * 2 + 0] = *(const i32x4*)(hrd + brow * 512 + k0);
        q[kt * 2 + 1] = *(const i32x4*)(hrd + 2048 + brow * 512 + k0);
      }
      unsigned bad = 0;
#pragma unroll
      for (int i = 0; i < 8; ++i)
#pragma unroll
        for (int j = 0; j < 4; ++j)
          bad |= (((unsigned)q[i][j]) & 0x00030003u) ^ tp32;
      ok = __all(bad == 0);
    }
    if (!ok) {
      const unsigned long long tp64 = 0x0001000100010001ull * (unsigned long long)tag;
      const unsigned long long* h64 = (const unsigned long long*)hrd;
      for (;;) {
        unsigned long long bad = 0;
#pragma unroll
        for (int kt = 0; kt < 4; ++kt) {
          const int k0 = (gw << 7) + (kt << 5) + kgrp;
          const int bi = (brow * 512 + k0) >> 2;
          const int bj = (2048 + brow * 512 + k0) >> 2;
          union { unsigned long long u[2]; i32x4 v; } a, b;
          a.u[0] = __hip_atomic_load(h64 + bi, __ATOMIC_RELAXED, __HIP_MEMORY_SCOPE_AGENT);
          a.u[1] = __hip_atomic_load(h64 + bi + 1, __ATOMIC_RELAXED, __HIP_MEMORY_SCOPE_AGENT);
          b.u[0] = __hip_atomic_load(h64 + bj, __ATOMIC_RELAXED, __HIP_MEMORY_SCOPE_AGENT);
          b.u[1] = __hip_atomic_load(h64 + bj + 1, __ATOMIC_RELAXED, __HIP_MEMORY_SCOPE_AGENT);
          q[kt * 2 + 0] = a.v;
          q[kt * 2 + 1] = b.v;
          bad |= (a.u[0] & 0x0003000300030003ull) ^ tp64;
          bad |= (a.u[1] & 0x0003000300030003ull) ^ tp64;
          bad |= (b.u[0] & 0x0003000300030003ull) ^ tp64;
          bad |= (b.u[1] & 0x0003000300030003ull) ^ tp64;
        }
        if (__all(bad == 0)) break;
        __builtin_amdgcn_s_sleep(1);
      }
    }

    // ---- phase D: h-part MFMAs
#pragma unroll
    for (int kt = 0; kt < 4; ++kt) {
      short8 hh = __builtin_bit_cast(short8, q[kt * 2 + 0]);
      short8 hl = __builtin_bit_cast(short8, q[kt * 2 + 1]);
#pragma unroll
      for (int nt = 0; nt < 4; ++nt) {
        acc[nt] = __builtin_amdgcn_mfma_f32_16x16x32_bf16(hh, whf[kt][nt], acc[nt], 0, 0, 0);
        acc[nt] = __builtin_amdgcn_mfma_f32_16x16x32_bf16(hl, whf[kt][nt], acc[nt], 0, 0, 0);
      }
    }

    // ---- phase E: K-partial exchange + gates (ONE barrier per step)
    if (lane < 16) {
#pragma unroll
      for (int nt = 0; nt < 4; ++nt)
#pragma unroll
        for (int r = 0; r < 4; ++r)
          gLDS[t & 1][gw][nt][r][lane] = acc[nt][r];
    }
    __syncthreads();

    float v4[4];
#pragma unroll
    for (int gg2 = 0; gg2 < 4; ++gg2) {
      float sum = bias4[gg2];
#pragma unroll
      for (int w = 0; w < 4; ++w) sum += gLDS[t & 1][w][gg2][gb][gu];
      v4[gg2] = sum;
    }
    float ig = fast_sigmoid(v4[0]);
    float fg = fast_sigmoid(v4[1]);
    float og = fast_sigmoid(v4[2]);
    float gg3 = fast_tanh(v4[3]);
    c = fg * c + ig * gg3;
    float h = og * fast_tanh(c);

    // ---- phase F: publish (wave 0): data stores -> vmcnt(0) -> flag bump
    if (gw == 0 && t + 1 < T_STEPS) {
      const unsigned ntag = (unsigned)(((t + 1) >> 4) & 3);
      float ha = __shfl(h, shfl_src);
      float hbv = __shfl(h, shfl_src + 1);
      unsigned short hiA = (unsigned short)((f2bf(ha) & 0xFFFCu) | ntag);
      unsigned short loA = (unsigned short)((f2bf(ha - bf2f(hiA)) & 0xFFFCu) | ntag);
      unsigned short hiB = (unsigned short)((f2bf(hbv) & 0xFFFCu) | ntag);
      unsigned short loB = (unsigned short)((f2bf(hbv - bf2f(hiB)) & 0xFFFCu) | ntag);
      unsigned whi = (unsigned)hiA | ((unsigned)hiB << 16);
      unsigned wlo = (unsigned)loA | ((unsigned)loB << 16);
      if (lane < 32) {
        const int b = lane >> 3, u2 = (lane & 7) * 2;
        unsigned short* wr = hb + ((t + 1) & 15) * 4096;
        if (use_direct) {
          *(unsigned*)&wr[b * 512 + s * 16 + u2] = whi;          // write-through -> L2
          *(unsigned*)&wr[2048 + b * 512 + s * 16 + u2] = wlo;
        } else {
          __hip_atomic_store((unsigned*)&wr[b * 512 + s * 16 + u2], whi,
                             __ATOMIC_RELAXED, __HIP_MEMORY_SCOPE_AGENT);
          __hip_atomic_store((unsigned*)&wr[2048 + b * 512 + s * 16 + u2], wlo,
                             __ATOMIC_RELAXED, __HIP_MEMORY_SCOPE_AGENT);
        }
      }
      asm volatile("s_waitcnt vmcnt(0)" ::: "memory");           // data visible first
      if (lane == 0) {
        int one = 1;
        asm volatile("global_atomic_add %0, %1, off" :: "v"(myflag), "v"(one) : "memory");
      }
    }

    // ---- phase G: out store + x prefetch (off the publish path)
    outbase[(size_t)t * 512] = h;
    {
      const int tn = (t + 1 < T_STEPS) ? (t + 1) : t;
      const unsigned short* xt1 = xb + (size_t)tn * 16384;
#pragma unroll
      for (int kt = 0; kt < 4; ++kt) {
        const int k0 = (gw << 7) + (kt << 5) + kgrp;
        xf[kt] = *(const short8*)&xt1[xrow + k0];
      }
    }
  }
}

extern "C" void kernel_launch(void* const* d_in, const int* in_sizes, int n_in,
                              void* d_out, int out_size, void* d_ws, size_t ws_size,
                              hipStream_t stream) {
  const float* x = (const float*)d_in[0];     // (32, 2048, 512) f32
  const float* h0 = (const float*)d_in[1];    // (32, 512) f32
  const float* Wx = (const float*)d_in[2];    // (512, 2048) f32
  const float* Wh = (const float*)d_in[3];    // (512, 2048) f32
  const float* bias = (const float*)d_in[4];  // (2048,) f32
  float* out = (float*)d_out;

  char* ws = (char*)d_ws;
  unsigned short* wxp = (unsigned short*)(ws);                            // 2 MB
  unsigned short* whp = (unsigned short*)(ws + (2u << 20));               // 2 MB
  unsigned short* hbuf = (unsigned short*)(ws + (4u << 20));              // 1 MB
  int* ctl = (int*)(ws + (5u << 20) + (512u << 10));                      // 36 B
  int* flags = (int*)(ws + (6u << 20));                                   // 32 KB
  unsigned short* xb = (unsigned short*)(ws + (8u << 20));                // 64 MB

  hipLaunchKernelGGL(prep_kernel, dim3(8289), dim3(256), 0, stream,
                     Wx, Wh, h0, wxp, whp, hbuf, ctl, flags);
  hipLaunchKernelGGL(xprep_kernel, dim3(16384), dim3(256), 0, stream, x, xb);
  hipLaunchKernelGGL(scan_kernel, dim3(256), dim3(256), 0, stream,
                     xb, bias, wxp, whp, hbuf, out, ctl, flags);
}

// Round 11
// 6269.189 us; speedup vs baseline: 1.8019x; 1.0539x over previous
//
#include <hip/hip_runtime.h>

typedef __attribute__((ext_vector_type(8))) short short8;       // bf16x8 MFMA frag
typedef __attribute__((ext_vector_type(8))) unsigned short ushort8;
typedef __attribute__((ext_vector_type(4))) float f32x4;
typedef __attribute__((ext_vector_type(4))) int i32x4;

#define T_STEPS 2048

static __device__ __forceinline__ unsigned short f2bf(float f) {
  unsigned u = __builtin_bit_cast(unsigned, f);
  unsigned r = u + 0x7fffu + ((u >> 16) & 1u);   // RNE
  return (unsigned short)(r >> 16);
}
static __device__ __forceinline__ float bf2f(unsigned short h) {
  unsigned u = ((unsigned)h) << 16;
  return __builtin_bit_cast(float, u);
}
static __device__ __forceinline__ float fast_sigmoid(float v) {
  return __builtin_amdgcn_rcpf(1.0f + __expf(-v));
}
static __device__ __forceinline__ float fast_tanh(float v) {
  return 1.0f - 2.0f * __builtin_amdgcn_rcpf(1.0f + __expf(2.0f * v));
}

// W pack (proven): p[s][g][kt][l][e], element = W[k][c],
// k = kt*32 + (l>>4)*8 + e ; c = g*512 + s*16 + (l&15).
//
// h exchange: per-GROUP 16-slot ring, hbuf[group][slot][plane][4*512] bf16;
// slot=t&15, tag=(t>>4)&3 in 2 LSBs of every ushort (self-validating).
// r11 protocol (all primitives session-proven):
//   consumer: SPECULATIVE plain 2KB read + tag check (usually hits: data is
//   L2-visible before the flag; L1 lines for this slot were capacity-evicted
//   during the 16-step ring lap). On miss: flag spin (4B RMWs, r10) then the
//   MALL agent-atomic data loop (r9, fresh+live — avoids the stale L1 line
//   the failed speculative read just allocated). Producer: plain data stores
//   -> vmcnt(0) -> one agent atomic flag bump. Hang-impossible by design.
__global__ void prep_kernel(const float* __restrict__ Wx, const float* __restrict__ Wh,
                            const float* __restrict__ h0,
                            unsigned short* __restrict__ wxp, unsigned short* __restrict__ whp,
                            unsigned short* __restrict__ hbuf, int* __restrict__ ctl,
                            int* __restrict__ flags) {
  int idx = blockIdx.x * 256 + threadIdx.x;
  if (idx < 2097152) {
    int which = idx >> 20;
    int r = idx & 1048575;
    int e = r & 7;
    int l = (r >> 3) & 63;
    int kt = (r >> 9) & 15;
    int g = (r >> 13) & 3;
    int s = r >> 15;
    int k = kt * 32 + ((l >> 4) << 3) + e;
    int c = g * 512 + s * 16 + (l & 15);
    const float* W = which ? Wh : Wx;
    unsigned short* dst = which ? whp : wxp;
    dst[r] = f2bf(W[k * 2048 + c]);
  } else if (idx < 2097152 + 16384) {
    int i = idx - 2097152;                 // b*512 + k
    int bg = i >> 9;
    int k = i & 511;
    int g = bg >> 2, bl = bg & 3;
    float v = h0[i];
    unsigned short hi = f2bf(v) & 0xFFFCu;                 // tag(step 0)=0
    unsigned short lo = f2bf(v - bf2f(hi)) & 0xFFFCu;
    unsigned short* d = hbuf + g * 65536;                  // group base, slot 0
    d[bl * 512 + k] = hi;
    d[2048 + bl * 512 + k] = lo;
  } else if (idx < 2097152 + 16384 + 9) {
    ctl[idx - (2097152 + 16384)] = 0;      // ctl[0..7]=XCD tickets, ctl[8]=orphan rank
  } else if (idx < 2097152 + 16384 + 9 + 8192) {
    flags[idx - (2097152 + 16384 + 9)] = 0;   // 8 groups x 32 slices x 32-int spacing
  }
}

// Transpose x (b,t,d) f32 -> xt (t,b,d) bf16 (unchanged).
__global__ void xprep_kernel(const float* __restrict__ x, unsigned short* __restrict__ xb) {
  size_t i8 = ((size_t)blockIdx.x * 256 + threadIdx.x) * 8;
  int t = (int)(i8 >> 14);
  int r = (int)(i8 & 16383);
  int b = r >> 9;
  int d = r & 511;
  const float* src = x + ((size_t)b * 2048 + (size_t)t) * 512 + d;
  f32x4 a = *(const f32x4*)src;
  f32x4 c = *(const f32x4*)(src + 4);
  ushort8 o;
#pragma unroll
  for (int e = 0; e < 4; ++e) {
    o[e] = f2bf(a[e]);
    o[e + 4] = f2bf(c[e]);
  }
  *(ushort8*)(xb + i8) = o;
}

__global__ __launch_bounds__(256, 1) void scan_kernel(
    const unsigned short* __restrict__ xb, const float* __restrict__ bias,
    const unsigned short* __restrict__ wxp, const unsigned short* __restrict__ whp,
    unsigned short* __restrict__ hbuf, float* __restrict__ out, int* __restrict__ ctl,
    int* __restrict__ flags) {
  __shared__ unsigned short WxL[4][16][512];   // 64 KB
  __shared__ unsigned short WhL[4][16][512];   // 64 KB
  __shared__ float gLDS[2][4][4][4][16];       // 8 KB [parity][wave][gate][batch][unit]
  __shared__ int s_g, s_s, s_dir;

  const int tid = threadIdx.x;
  const int lane = tid & 63;
  const int gw = tid >> 6;                     // wave id == K-slice id

  if (tid == 0) {
    unsigned xcc;
    asm volatile("s_getreg_b32 %0, hwreg(HW_REG_XCC_ID)" : "=s"(xcc));
    xcc &= 7;
    int tk = __hip_atomic_fetch_add(&ctl[xcc], 1, __ATOMIC_RELAXED,
                                    __HIP_MEMORY_SCOPE_AGENT);
    int c[8];
    for (;;) {                                 // settle: all 256 ticket first
      int tot = 0;
#pragma unroll
      for (int x = 0; x < 8; ++x) {
        c[x] = __hip_atomic_load(&ctl[x], __ATOMIC_RELAXED, __HIP_MEMORY_SCOPE_AGENT);
        tot += c[x];
      }
      if (tot >= 256) break;
      __builtin_amdgcn_s_sleep(2);
    }
    int g = -1, s = -1, dir = 0;
    if (tk < 32) {
      g = (int)xcc;
      s = tk;
      dir = (c[xcc] >= 32);                    // fully local group => L2 fast path
    } else {
      int rank = __hip_atomic_fetch_add(&ctl[8], 1, __ATOMIC_RELAXED,
                                        __HIP_MEMORY_SCOPE_AGENT);
      int acc2 = 0;
      for (int x = 0; x < 8; ++x) {
        int n = 32 - c[x];
        if (n < 0) n = 0;
        if (g < 0 && rank < acc2 + n) { g = x; s = c[x] + (rank - acc2); }
        acc2 += n;
      }
      dir = 0;
    }
    s_g = g; s_s = s; s_dir = dir;
  }
  __syncthreads();
  const int g = s_g, s = s_s, use_direct = s_dir;
  if (s < 0 || g < 0) return;

  {
    const ushort8* sx = (const ushort8*)(wxp + (size_t)s * 32768);
    const ushort8* sh = (const ushort8*)(whp + (size_t)s * 32768);
    ushort8* dx = (ushort8*)&WxL[0][0][0];
    ushort8* dh = (ushort8*)&WhL[0][0][0];
    for (int i = tid; i < 4096; i += 256) {
      dx[i] = sx[i];
      dh[i] = sh[i];
    }
  }
  __syncthreads();
  short8 wxf[4][4], whf[4][4];                 // [kt][nt]
#pragma unroll
  for (int kt = 0; kt < 4; ++kt)
#pragma unroll
    for (int nt = 0; nt < 4; ++nt) {
      const int ktg = (gw << 2) + kt;
      wxf[kt][nt] = *(const short8*)&WxL[nt][ktg][lane * 8];
      whf[kt][nt] = *(const short8*)&WhL[nt][ktg][lane * 8];
    }

  const int brow = lane & 3;
  const int kgrp = (lane >> 4) * 8;
  const int gb = lane >> 4;                    // gate-phase batch 0..3
  const int gu = lane & 15;                    // gate-phase unit 0..15
  float bias4[4];
#pragma unroll
  for (int gg2 = 0; gg2 < 4; ++gg2)
    bias4[gg2] = bias[gg2 * 512 + s * 16 + gu];
  float c = 0.f;

  unsigned short* hb = hbuf + g * 65536;
  int* gflags = flags + g * 1024;
  int* wflag = gflags + ((gw << 3) + (lane & 7)) * 32;   // my wave's 8 producers
  int* myflag = gflags + s * 32;
  float* outbase = out + (size_t)(g * 4 + gb) * (2048 * 512) + s * 16 + gu;
  const int xrow = (g * 4 + brow) * 512;
  const int shfl_src = ((lane >> 3) << 4) + ((lane & 7) << 1);

  short8 xf[4];
#pragma unroll
  for (int kt = 0; kt < 4; ++kt) {
    const int k0 = (gw << 7) + (kt << 5) + kgrp;
    xf[kt] = *(const short8*)&xb[xrow + k0];
  }

  for (int t = 0; t < T_STEPS; ++t) {
    // ---- phase A: x-part MFMAs (h-independent; shadow work)
    f32x4 acc[4], accl[4];
#pragma unroll
    for (int nt = 0; nt < 4; ++nt) {
      acc[nt] = (f32x4){0.f, 0.f, 0.f, 0.f};
      accl[nt] = (f32x4){0.f, 0.f, 0.f, 0.f};
    }
#pragma unroll
    for (int kt = 0; kt < 4; ++kt)
#pragma unroll
      for (int nt = 0; nt < 4; ++nt)
        acc[nt] = __builtin_amdgcn_mfma_f32_16x16x32_bf16(xf[kt], wxf[kt][nt], acc[nt], 0, 0, 0);

    // ---- phase B: speculative tagged data read (flag-free common case)
    const unsigned tag = (unsigned)((t >> 4) & 3);
    const unsigned tp32 = 0x00010001u * tag;
    const unsigned short* hrd = hb + (t & 15) * 4096;
    i32x4 q[8];
    bool ok = false;
    if (use_direct) {
#pragma unroll
      for (int kt = 0; kt < 4; ++kt) {
        const int k0 = (gw << 7) + (kt << 5) + kgrp;
        q[kt * 2 + 0] = *(const i32x4*)(hrd + brow * 512 + k0);
        q[kt * 2 + 1] = *(const i32x4*)(hrd + 2048 + brow * 512 + k0);
      }
      unsigned bad = 0;
#pragma unroll
      for (int i = 0; i < 8; ++i)
#pragma unroll
        for (int j = 0; j < 4; ++j)
          bad |= (((unsigned)q[i][j]) & 0x00030003u) ^ tp32;
      ok = __all(bad == 0);
    }

    if (!ok) {
      // miss path: flag spin (cheap 4B RMWs), then MALL data loop (fresh).
      if (use_direct && t > 0) {
        int done = (lane >= 8);
        for (;;) {
          if (!done) {
            int old, zero = 0;
            asm volatile("global_atomic_add %0, %1, %2, off sc0\n\t"
                         "s_waitcnt vmcnt(0)"
                         : "=v"(old) : "v"(wflag), "v"(zero) : "memory");
            done = (old >= t);
          }
          if (__all(done)) break;
          __builtin_amdgcn_s_sleep(1);
        }
      }
      const unsigned long long tp64 = 0x0001000100010001ull * (unsigned long long)tag;
      const unsigned long long* h64 = (const unsigned long long*)hrd;
      for (;;) {
        unsigned long long bad = 0;
#pragma unroll
        for (int kt = 0; kt < 4; ++kt) {
          const int k0 = (gw << 7) + (kt << 5) + kgrp;
          const int bi = (brow * 512 + k0) >> 2;
          const int bj = (2048 + brow * 512 + k0) >> 2;
          union { unsigned long long u[2]; i32x4 v; } a, b;
          a.u[0] = __hip_atomic_load(h64 + bi, __ATOMIC_RELAXED, __HIP_MEMORY_SCOPE_AGENT);
          a.u[1] = __hip_atomic_load(h64 + bi + 1, __ATOMIC_RELAXED, __HIP_MEMORY_SCOPE_AGENT);
          b.u[0] = __hip_atomic_load(h64 + bj, __ATOMIC_RELAXED, __HIP_MEMORY_SCOPE_AGENT);
          b.u[1] = __hip_atomic_load(h64 + bj + 1, __ATOMIC_RELAXED, __HIP_MEMORY_SCOPE_AGENT);
          q[kt * 2 + 0] = a.v;
          q[kt * 2 + 1] = b.v;
          bad |= (a.u[0] & 0x0003000300030003ull) ^ tp64;
          bad |= (a.u[1] & 0x0003000300030003ull) ^ tp64;
          bad |= (b.u[0] & 0x0003000300030003ull) ^ tp64;
          bad |= (b.u[1] & 0x0003000300030003ull) ^ tp64;
        }
        if (__all(bad == 0)) break;
        __builtin_amdgcn_s_sleep(1);
      }
    }

    // ---- phase D: h-part MFMAs (split chains: hh->acc, hl->accl)
#pragma unroll
    for (int kt = 0; kt < 4; ++kt) {
      short8 hh = __builtin_bit_cast(short8, q[kt * 2 + 0]);
      short8 hl = __builtin_bit_cast(short8, q[kt * 2 + 1]);
#pragma unroll
      for (int nt = 0; nt < 4; ++nt) {
        acc[nt] = __builtin_amdgcn_mfma_f32_16x16x32_bf16(hh, whf[kt][nt], acc[nt], 0, 0, 0);
        accl[nt] = __builtin_amdgcn_mfma_f32_16x16x32_bf16(hl, whf[kt][nt], accl[nt], 0, 0, 0);
      }
    }

    // ---- phase E: K-partial exchange + gates (ONE barrier per step)
    if (lane < 16) {
#pragma unroll
      for (int nt = 0; nt < 4; ++nt)
#pragma unroll
        for (int r = 0; r < 4; ++r)
          gLDS[t & 1][gw][nt][r][lane] = acc[nt][r] + accl[nt][r];
    }
    __syncthreads();

    float v4[4];
#pragma unroll
    for (int gg2 = 0; gg2 < 4; ++gg2) {
      float sum = bias4[gg2];
#pragma unroll
      for (int w = 0; w < 4; ++w) sum += gLDS[t & 1][w][gg2][gb][gu];
      v4[gg2] = sum;
    }
    float ig = fast_sigmoid(v4[0]);
    float fg = fast_sigmoid(v4[1]);
    float og = fast_sigmoid(v4[2]);
    float gg3 = fast_tanh(v4[3]);
    c = fg * c + ig * gg3;
    float h = og * fast_tanh(c);

    // ---- phase F: publish (wave 0): data stores -> vmcnt(0) -> flag bump
    if (gw == 0 && t + 1 < T_STEPS) {
      const unsigned ntag = (unsigned)(((t + 1) >> 4) & 3);
      float ha = __shfl(h, shfl_src);
      float hbv = __shfl(h, shfl_src + 1);
      unsigned short hiA = (unsigned short)((f2bf(ha) & 0xFFFCu) | ntag);
      unsigned short loA = (unsigned short)((f2bf(ha - bf2f(hiA)) & 0xFFFCu) | ntag);
      unsigned short hiB = (unsigned short)((f2bf(hbv) & 0xFFFCu) | ntag);
      unsigned short loB = (unsigned short)((f2bf(hbv - bf2f(hiB)) & 0xFFFCu) | ntag);
      unsigned whi = (unsigned)hiA | ((unsigned)hiB << 16);
      unsigned wlo = (unsigned)loA | ((unsigned)loB << 16);
      if (lane < 32) {
        const int b = lane >> 3, u2 = (lane & 7) * 2;
        unsigned short* wr = hb + ((t + 1) & 15) * 4096;
        if (use_direct) {
          *(unsigned*)&wr[b * 512 + s * 16 + u2] = whi;          // write-through -> L2
          *(unsigned*)&wr[2048 + b * 512 + s * 16 + u2] = wlo;
        } else {
          __hip_atomic_store((unsigned*)&wr[b * 512 + s * 16 + u2], whi,
                             __ATOMIC_RELAXED, __HIP_MEMORY_SCOPE_AGENT);
          __hip_atomic_store((unsigned*)&wr[2048 + b * 512 + s * 16 + u2], wlo,
                             __ATOMIC_RELAXED, __HIP_MEMORY_SCOPE_AGENT);
        }
      }
      asm volatile("s_waitcnt vmcnt(0)" ::: "memory");           // data visible first
      if (lane == 0) {
        int one = 1;
        asm volatile("global_atomic_add %0, %1, off" :: "v"(myflag), "v"(one) : "memory");
      }
    }

    // ---- phase G: out store (wave 1 ONLY — no redundant writes) + x prefetch
    if (gw == 1) outbase[(size_t)t * 512] = h;
    {
      const int tn = (t + 1 < T_STEPS) ? (t + 1) : t;
      const unsigned short* xt1 = xb + (size_t)tn * 16384;
#pragma unroll
      for (int kt = 0; kt < 4; ++kt) {
        const int k0 = (gw << 7) + (kt << 5) + kgrp;
        xf[kt] = *(const short8*)&xt1[xrow + k0];
      }
    }
  }
}

extern "C" void kernel_launch(void* const* d_in, const int* in_sizes, int n_in,
                              void* d_out, int out_size, void* d_ws, size_t ws_size,
                              hipStream_t stream) {
  const float* x = (const float*)d_in[0];     // (32, 2048, 512) f32
  const float* h0 = (const float*)d_in[1];    // (32, 512) f32
  const float* Wx = (const float*)d_in[2];    // (512, 2048) f32
  const float* Wh = (const float*)d_in[3];    // (512, 2048) f32
  const float* bias = (const float*)d_in[4];  // (2048,) f32
  float* out = (float*)d_out;

  char* ws = (char*)d_ws;
  unsigned short* wxp = (unsigned short*)(ws);                            // 2 MB
  unsigned short* whp = (unsigned short*)(ws + (2u << 20));               // 2 MB
  unsigned short* hbuf = (unsigned short*)(ws + (4u << 20));              // 1 MB
  int* ctl = (int*)(ws + (5u << 20) + (512u << 10));                      // 36 B
  int* flags = (int*)(ws + (6u << 20));                                   // 32 KB
  unsigned short* xb = (unsigned short*)(ws + (8u << 20));                // 64 MB

  hipLaunchKernelGGL(prep_kernel, dim3(8289), dim3(256), 0, stream,
                     Wx, Wh, h0, wxp, whp, hbuf, ctl, flags);
  hipLaunchKernelGGL(xprep_kernel, dim3(16384), dim3(256), 0, stream, x, xb);
  hipLaunchKernelGGL(scan_kernel, dim3(256), dim3(256), 0, stream,
                     xb, bias, wxp, whp, hbuf, out, ctl, flags);
}